// Round 1
// baseline (4215.680 us; speedup 1.0000x reference)
//
#include <hip/hip_runtime.h>

#define H 384
#define EPS 1e-5f

typedef __attribute__((ext_vector_type(8))) short bf8v;            // 8 bf16
typedef __attribute__((ext_vector_type(8))) unsigned short us8;
typedef __attribute__((ext_vector_type(4))) float f32x4;

__device__ __forceinline__ float b2f(unsigned short b) {
    return __builtin_bit_cast(float, (unsigned)b << 16);
}
__device__ __forceinline__ unsigned short f2b(float f) {
    unsigned u = __builtin_bit_cast(unsigned, f);
    u += 0x7FFFu + ((u >> 16) & 1u);          // RNE
    return (unsigned short)(u >> 16);
}

// async global->LDS, 16B per lane; LDS dest = wave-uniform base + lane*16
__device__ __forceinline__ void gload16(const unsigned short* g, unsigned short* l) {
    __builtin_amdgcn_global_load_lds(
        (const __attribute__((address_space(1))) void*)g,
        (__attribute__((address_space(3))) void*)l, 16, 0, 0);
}

// ---------------------------------------------------------------------------
// bf16 MFMA GEMM: Cb = A1@W1t^T [+ A2@W2t^T] + bias (bf16 out, optional relu).
// Optional fused BN stats: per-column sum/sumsq of fp32 (acc+bias) -> atomics.
// A [Nr,K] bf16 row-major; Wt [M,K] bf16 row-major. 128x128 tile, 4 waves.
// BK=64, global_load_lds staging into linear LDS with XOR-swizzled source
// (chunk ^= row&7), matching XOR on ds_read_b128 -> conflict-free fragments.
// Epilogue stages C tile in LDS (stride 136) -> coalesced 16B/lane stores.
// ---------------------------------------------------------------------------
__global__ __launch_bounds__(256) void gemm_mfma(
    const unsigned short* __restrict__ A1, const unsigned short* __restrict__ W1t,
    const unsigned short* __restrict__ A2, const unsigned short* __restrict__ W2t,
    const float* __restrict__ bias, unsigned short* __restrict__ Cb,
    float* __restrict__ bnsum, float* __restrict__ bnsq,
    int Nr, int K, int M, int relu)
{
    __shared__ unsigned short smem[17408];   // A[128][64] | B[128][64] ; reused as C[128][136]
    __shared__ float s_stat[256];            // 128 sum + 128 sumsq
    unsigned short* sA = smem;               // 8192 ushorts
    unsigned short* sB = smem + 8192;
    const int t = threadIdx.x;
    const int wave = t >> 6, lane = t & 63;
    const int wr = (wave >> 1) * 64, wc = (wave & 1) * 64;
    const int c0 = blockIdx.x * 128, r0 = blockIdx.y * 128;
    const int lm = lane & 15, lq = lane >> 4;
    const int l8 = lane >> 3;                 // 0..7 (row within 8-row segment)
    const int gsw8 = ((lane & 7) ^ l8) * 8;   // pre-swizzled source chunk (elements)
    f32x4 acc[4][4] = {};

    s_stat[t] = 0.f;  // visible before epilogue via in-loop barriers

    const int npass = (A2 != nullptr) ? 2 : 1;
    for (int pass = 0; pass < npass; ++pass) {
        const unsigned short* __restrict__ A = pass ? A2 : A1;
        const unsigned short* __restrict__ W = pass ? W2t : W1t;
        for (int k0 = 0; k0 < K; k0 += 64) {
            #pragma unroll
            for (int s = 0; s < 4; ++s) {
                const int seg = (wave << 2) + s;        // 0..15
                const int tr = (seg << 3) + l8;         // tile row 0..127
                int gr = r0 + tr; if (gr >= Nr) gr = Nr - 1;
                gload16(A + (long)gr * K + k0 + gsw8, sA + (seg << 9));
                int gc = c0 + tr; if (gc >= M) gc = M - 1;
                gload16(W + (long)gc * K + k0 + gsw8, sB + (seg << 9));
            }
            __syncthreads();
            #pragma unroll
            for (int kk = 0; kk < 2; ++kk) {
                const int pc = (((kk << 2) | lq) ^ (lm & 7)) << 3;  // phys chunk (elements)
                bf8v af[4], bf[4];
                #pragma unroll
                for (int i = 0; i < 4; ++i) {
                    const int ra = wr + (i << 4) + lm;
                    af[i] = *(const bf8v*)(sA + (ra << 6) + pc);
                    const int rb = wc + (i << 4) + lm;
                    bf[i] = *(const bf8v*)(sB + (rb << 6) + pc);
                }
                #pragma unroll
                for (int i = 0; i < 4; ++i)
                    #pragma unroll
                    for (int j = 0; j < 4; ++j)
                        acc[i][j] = __builtin_amdgcn_mfma_f32_16x16x32_bf16(
                            af[i], bf[j], acc[i][j], 0, 0, 0);
            }
            __syncthreads();
        }
    }

    const bool do_stats = (bnsum != nullptr);
    unsigned short* sC = smem;               // [128][136] bf16

    // ---- epilogue phase 1: bias/relu, BN partial stats, stage C tile in LDS
    #pragma unroll
    for (int jj = 0; jj < 4; ++jj) {
        const int j = (jj + lq) & 3;         // lq-stagger -> bank spread on writes
        const int lcol = wc + (j << 4) + lm;
        const int col = c0 + lcol;
        const float bi = (col < M) ? bias[col] : 0.f;
        float ls = 0.f, lss = 0.f;
        #pragma unroll
        for (int i = 0; i < 4; ++i) {
            const int lrow = wr + (i << 4) + (lq << 2);
            #pragma unroll
            for (int r = 0; r < 4; ++r) {
                float v = acc[i][j][r] + bi;
                if (r0 + lrow + r < Nr) { ls += v; lss += v * v; }
                sC[(lrow + r) * 136 + lcol] = f2b(relu ? fmaxf(v, 0.f) : v);
            }
        }
        if (do_stats && col < M) {
            atomicAdd(&s_stat[lcol], ls);
            atomicAdd(&s_stat[128 + lcol], lss);
        }
    }
    __syncthreads();
    if (do_stats && t < 128) {
        int col = c0 + t;
        if (col < M) {
            atomicAdd(&bnsum[col], s_stat[t]);
            atomicAdd(&bnsq[col], s_stat[128 + t]);
        }
    }
    // ---- epilogue phase 2: coalesced row-major stores (16B/lane)
    #pragma unroll
    for (int it = 0; it < 8; ++it) {
        const int idx = (it << 8) + t;       // 0..2047
        const int lrow = idx >> 4;           // 0..127
        const int ch = idx & 15;             // 16B chunk in 256B row
        const int rowg = r0 + lrow;
        const int col = c0 + (ch << 3);
        if (rowg < Nr && col < M)
            *(bf8v*)(Cb + (long)rowg * M + col) =
                *(const bf8v*)(sC + lrow * 136 + (ch << 3));
    }
}

// ---------------------------------------------------------------------------
// Weight convert+transpose: W [L][K][M] fp32 -> Wt [L][M][K] bf16
// ---------------------------------------------------------------------------
__global__ void wt_convert(const float* __restrict__ W, unsigned short* __restrict__ Wt,
                           int total, int K, int M)
{
    int idx = blockIdx.x * 256 + threadIdx.x;
    if (idx >= total) return;
    int l = idx / (K * M), rem = idx - l * K * M;
    int k = rem / M, m = rem - k * M;
    Wt[(long)l * K * M + (long)m * K + k] = f2b(W[idx]);
}

__global__ void f2b_vec(const float* __restrict__ X, unsigned short* __restrict__ Y, int n4)
{
    int idx = blockIdx.x * 256 + threadIdx.x;
    if (idx >= n4) return;
    float4 v = *(const float4*)(X + idx * 4);
    ushort4 o = {f2b(v.x), f2b(v.y), f2b(v.z), f2b(v.w)};
    *(ushort4*)(Y + idx * 4) = o;
}

// ---------------------------------------------------------------------------
// CSR construction
// ---------------------------------------------------------------------------
__global__ void count_edges_i(const int* __restrict__ col, int* __restrict__ cnt, int E)
{
    int e = blockIdx.x * 256 + threadIdx.x;
    if (e < E) atomicAdd(&cnt[col[e]], 1);
}

__global__ __launch_bounds__(1024) void exscan_csr(const int* __restrict__ cnt,
                                                   int* __restrict__ offs, int n)
{
    __shared__ int s[1024];
    const int t = threadIdx.x;
    const int chunk = (n + 1023) >> 10;
    int lo = t * chunk, hi = lo + chunk;
    if (lo > n) lo = n;
    if (hi > n) hi = n;
    int sum = 0;
    for (int i = lo; i < hi; ++i) sum += cnt[i];
    s[t] = sum;
    __syncthreads();
    for (int d = 1; d < 1024; d <<= 1) {
        int o = (t >= d) ? s[t - d] : 0;
        __syncthreads();
        s[t] += o;
        __syncthreads();
    }
    int base = (t == 0) ? 0 : s[t - 1];
    for (int i = lo; i < hi; ++i) { offs[i] = base; base += cnt[i]; }
    if (t == 1023) offs[n] = s[1023];
}

__global__ void fill_csr(const int* __restrict__ row, const int* __restrict__ col,
                         const int* __restrict__ offs, int* __restrict__ cursor,
                         int* __restrict__ csr_rows, int E)
{
    int e = blockIdx.x * 256 + threadIdx.x;
    if (e < E) {
        int c = col[e];
        int p = offs[c] + atomicAdd(&cursor[c], 1);
        csr_rows[p] = row[e];
    }
}

__global__ void inv_from_cnt(const int* __restrict__ cnt, float* __restrict__ inv, int n)
{
    int i = blockIdx.x * 256 + threadIdx.x;
    if (i < n) inv[i] = 1.0f / fmaxf((float)cnt[i], 1.0f);
}

// ---------------------------------------------------------------------------
// CSR gather-mean in bf16: 8 nodes/block, 48 lanes/node, us8/lane, unroll x4
// ---------------------------------------------------------------------------
__global__ __launch_bounds__(384) void agg_gather(
    const unsigned short* __restrict__ hb, const int* __restrict__ csr_rows,
    const int* __restrict__ offs, const float* __restrict__ inv,
    unsigned short* __restrict__ aggb, int N)
{
    int g = threadIdx.x / 48;
    int lane = threadIdx.x - g * 48;
    int node = blockIdx.x * 8 + g;
    if (node >= N) return;
    const int lo = offs[node], hi = offs[node + 1];
    float s[8] = {};
    int e = lo;
    for (; e + 3 < hi; e += 4) {
        int r0 = csr_rows[e], r1 = csr_rows[e + 1];
        int r2 = csr_rows[e + 2], r3 = csr_rows[e + 3];
        us8 v0 = *(const us8*)(hb + (long)r0 * H + lane * 8);
        us8 v1 = *(const us8*)(hb + (long)r1 * H + lane * 8);
        us8 v2 = *(const us8*)(hb + (long)r2 * H + lane * 8);
        us8 v3 = *(const us8*)(hb + (long)r3 * H + lane * 8);
        #pragma unroll
        for (int q = 0; q < 8; ++q)
            s[q] += (b2f(v0[q]) + b2f(v1[q])) + (b2f(v2[q]) + b2f(v3[q]));
    }
    for (; e < hi; ++e) {
        us8 v = *(const us8*)(hb + (long)csr_rows[e] * H + lane * 8);
        #pragma unroll
        for (int q = 0; q < 8; ++q) s[q] += b2f(v[q]);
    }
    float sc = inv[node];
    us8 o;
    #pragma unroll
    for (int q = 0; q < 8; ++q) o[q] = f2b(s[q] * sc);
    *(us8*)(aggb + (long)node * H + lane * 8) = o;
}

// ---------------------------------------------------------------------------
// Fused BN finalize+apply: outb = relu(X*scale+shift) [+S]; optional fp32 copy
// X is bf16 (pre-BN); stats were accumulated in fp32 by the GEMM epilogue.
// ---------------------------------------------------------------------------
__global__ __launch_bounds__(256) void bn_apply(
    const unsigned short* __restrict__ X, const float* __restrict__ bnsum,
    const float* __restrict__ bnsq, const float* __restrict__ g,
    const float* __restrict__ b, const unsigned short* __restrict__ S,
    unsigned short* __restrict__ outb, float* __restrict__ outf,
    int Nr, int total4)
{
    __shared__ float sc[H], sh[H];
    const int t = threadIdx.x;
    for (int j = t; j < H; j += 256) {
        float mu  = bnsum[j] / (float)Nr;
        float var = bnsq[j] / (float)Nr - mu * mu;
        float s   = g[j] * rsqrtf(fmaxf(var, 0.f) + EPS);
        sc[j] = s;
        sh[j] = b[j] - mu * s;
    }
    __syncthreads();
    int idx = blockIdx.x * 256 + t;
    if (idx >= total4) return;
    int base = idx * 4;
    int j = base % H;
    ushort4 v = *(const ushort4*)(X + base);
    float o0 = fmaxf(b2f(v.x) * sc[j + 0] + sh[j + 0], 0.f);
    float o1 = fmaxf(b2f(v.y) * sc[j + 1] + sh[j + 1], 0.f);
    float o2 = fmaxf(b2f(v.z) * sc[j + 2] + sh[j + 2], 0.f);
    float o3 = fmaxf(b2f(v.w) * sc[j + 3] + sh[j + 3], 0.f);
    if (S) {
        ushort4 s4 = *(const ushort4*)(S + base);
        o0 += b2f(s4.x); o1 += b2f(s4.y); o2 += b2f(s4.z); o3 += b2f(s4.w);
    }
    ushort4 o = {f2b(o0), f2b(o1), f2b(o2), f2b(o3)};
    *(ushort4*)(outb + base) = o;
    if (outf) {
        float4 of = {o0, o1, o2, o3};
        *(float4*)(outf + base) = of;
    }
}

// ---------------------------------------------------------------------------
// Final tiny layer: out[N,2] = m2[N,96] @ W3[96,2] + b3
// ---------------------------------------------------------------------------
__global__ void mlp3(const unsigned short* __restrict__ m2, const float* __restrict__ W3,
                     const float* __restrict__ b3, float* __restrict__ out, int N)
{
    int n = blockIdx.x * 256 + threadIdx.x;
    if (n >= N) return;
    float a0 = b3[0], a1 = b3[1];
    const unsigned short* r = m2 + (long)n * 96;
    #pragma unroll 4
    for (int k = 0; k < 96; ++k) {
        float v = b2f(r[k]);
        a0 += v * W3[k * 2];
        a1 += v * W3[k * 2 + 1];
    }
    out[n * 2 + 0] = a0;
    out[n * 2 + 1] = a1;
}

// ---------------------------------------------------------------------------
extern "C" void kernel_launch(void* const* d_in, const int* in_sizes, int n_in,
                              void* d_out, int out_size, void* d_ws, size_t ws_size,
                              hipStream_t stream)
{
    const float* x     = (const float*)d_in[0];
    const int*   ei    = (const int*)d_in[1];
    const float* W_in  = (const float*)d_in[2];
    const float* b_in  = (const float*)d_in[3];
    const float* bn0_g = (const float*)d_in[4];
    const float* bn0_b = (const float*)d_in[5];
    const float* Wl    = (const float*)d_in[6];
    const float* bl    = (const float*)d_in[7];
    const float* Wr    = (const float*)d_in[8];
    const float* bn_g  = (const float*)d_in[9];
    const float* bn_b  = (const float*)d_in[10];
    const float* Wskip = (const float*)d_in[11];
    const float* bskip = (const float*)d_in[12];
    const float* W1    = (const float*)d_in[13];
    const float* b1    = (const float*)d_in[14];
    const float* W2    = (const float*)d_in[15];
    const float* b2    = (const float*)d_in[16];
    const float* W3    = (const float*)d_in[17];
    const float* b3    = (const float*)d_in[18];

    const int DIN = 256;
    const int N = in_sizes[0] / DIN;
    const int E = in_sizes[1] / 2;
    const int* row = ei;
    const int* col = ei + E;
    const long NH = (long)N * H;

    // workspace layout: 16B-aligned bf16 buffers first, then weights, then ints
    unsigned short* tmp      = (unsigned short*)d_ws;             // [N,H] pre-BN
    unsigned short* hb       = tmp + NH;                          // [N,H]
    unsigned short* aggb     = hb + NH;                           // [N,H]
    unsigned short* Sbuf     = aggb + NH;                         // [N,H]
    unsigned short* xb       = Sbuf + NH;                         // [N,DIN]
    unsigned short* Wint     = xb + (long)N * DIN;                // [H,DIN]
    unsigned short* Wlt      = Wint + (long)H * DIN;              // 6 [H,H]
    unsigned short* Wrt      = Wlt + 6L * H * H;
    unsigned short* Wskipt   = Wrt + 6L * H * H;                  // 3 [H,H]
    unsigned short* W1t      = Wskipt + 3L * H * H;               // [192,H]
    unsigned short* W2t      = W1t + 192L * H;                    // [96,192]
    float*          inv      = (float*)(W2t + 96L * 192);
    int*            offs     = (int*)(inv + N);                   // N+1
    int*            csr_rows = offs + (N + 1);                    // E
    int*            cnt      = csr_rows + E;                      // N (zeroed)
    int*            cursor   = cnt + N;                           // N (zeroed)
    float*          stats    = (float*)(cursor + N);              // 14*H (zeroed)
    float* out = (float*)d_out;
    float* emb = out + (long)N * 2;

    dim3 blk(256);
    const int rg128 = (N + 127) / 128;
    const int app_grid = (int)((NH / 4 + 255) / 256);

    // single upfront zero of cnt+cursor+stats
    hipMemsetAsync(cnt, 0, (2L * N + 14 * H) * sizeof(float), stream);

    // ---- CSR build
    count_edges_i<<<(E + 255) / 256, blk, 0, stream>>>(col, cnt, E);
    exscan_csr<<<1, 1024, 0, stream>>>(cnt, offs, N);
    inv_from_cnt<<<(N + 255) / 256, blk, 0, stream>>>(cnt, inv, N);
    fill_csr<<<(E + 255) / 256, blk, 0, stream>>>(row, col, offs, cursor, csr_rows, E);

    // ---- weight convert+transpose
    {
        int n1 = H * DIN;
        wt_convert<<<(n1 + 255) / 256, blk, 0, stream>>>(W_in, Wint, n1, DIN, H);
        int n2 = 6 * H * H;
        wt_convert<<<(n2 + 255) / 256, blk, 0, stream>>>(Wl, Wlt, n2, H, H);
        wt_convert<<<(n2 + 255) / 256, blk, 0, stream>>>(Wr, Wrt, n2, H, H);
        int n3 = 3 * H * H;
        wt_convert<<<(n3 + 255) / 256, blk, 0, stream>>>(Wskip, Wskipt, n3, H, H);
        int n4 = H * 192;
        wt_convert<<<(n4 + 255) / 256, blk, 0, stream>>>(W1, W1t, n4, H, 192);
        int n5 = 192 * 96;
        wt_convert<<<(n5 + 255) / 256, blk, 0, stream>>>(W2, W2t, n5, 192, 96);
    }

    // ---- input layer: x->bf16 -> GEMM(+stats0) -> bn_apply -> hb
    {
        int n4 = N * DIN / 4;
        f2b_vec<<<(n4 + 255) / 256, blk, 0, stream>>>(x, xb, n4);
    }
    gemm_mfma<<<dim3(3, rg128), blk, 0, stream>>>(
        xb, Wint, nullptr, nullptr, b_in, tmp, stats, stats + H, N, DIN, H, 0);
    bn_apply<<<app_grid, blk, 0, stream>>>(
        tmp, stats, stats + H, bn0_g, bn0_b, nullptr, hb, nullptr, N, (int)(NH / 4));

    // ---- 6 SAGE layers
    int skip_idx = 0;
    for (int i = 0; i < 6; ++i) {
        float* bs = stats + (i + 1) * 2 * H;
        agg_gather<<<(N + 7) / 8, 384, 0, stream>>>(hb, csr_rows, offs, inv, aggb, N);

        // tmp = agg@Wl + h@Wr + bl  (+ fused BN stats)
        gemm_mfma<<<dim3(3, rg128), blk, 0, stream>>>(
            aggb, Wlt + (long)i * H * H, hb, Wrt + (long)i * H * H,
            bl + i * H, tmp, bs, bs + H, N, H, H, 0);

        const unsigned short* S = nullptr;
        if ((i & 1) == 1) {
            // separate skip GEMM: Sbuf = h@Wskip + bskip (no stats)
            gemm_mfma<<<dim3(3, rg128), blk, 0, stream>>>(
                hb, Wskipt + (long)skip_idx * H * H, nullptr, nullptr,
                bskip + skip_idx * H, Sbuf, nullptr, nullptr, N, H, H, 0);
            skip_idx++;
            S = Sbuf;
        }
        bn_apply<<<app_grid, blk, 0, stream>>>(
            tmp, bs, bs + H, bn_g + i * H, bn_b + i * H, S, hb,
            (i == 5) ? emb : nullptr, N, (int)(NH / 4));
    }

    // ---- MLP head
    unsigned short* m1b = aggb;    // [N,192] bf16
    unsigned short* m2b = tmp;     // [N,96] bf16
    gemm_mfma<<<dim3(2, rg128), blk, 0, stream>>>(
        hb, W1t, nullptr, nullptr, b1, m1b, nullptr, nullptr, N, H, 192, 1);
    gemm_mfma<<<dim3(1, rg128), blk, 0, stream>>>(
        m1b, W2t, nullptr, nullptr, b2, m2b, nullptr, nullptr, N, 192, 96, 1);
    mlp3<<<(N + 255) / 256, blk, 0, stream>>>(m2b, W3, b3, out, N);
}

// Round 2
// 1507.473 us; speedup vs baseline: 2.7965x; 2.7965x over previous
//
#include <hip/hip_runtime.h>

#define H 384
#define EPS 1e-5f

typedef __attribute__((ext_vector_type(8))) short bf8v;            // 8 bf16
typedef __attribute__((ext_vector_type(8))) unsigned short us8;
typedef __attribute__((ext_vector_type(4))) float f32x4;

__device__ __forceinline__ float b2f(unsigned short b) {
    return __builtin_bit_cast(float, (unsigned)b << 16);
}
__device__ __forceinline__ unsigned short f2b(float f) {
    unsigned u = __builtin_bit_cast(unsigned, f);
    u += 0x7FFFu + ((u >> 16) & 1u);          // RNE
    return (unsigned short)(u >> 16);
}

// async global->LDS, 16B per lane; LDS dest = wave-uniform base + lane*16
__device__ __forceinline__ void gload16(const unsigned short* g, unsigned short* l) {
    __builtin_amdgcn_global_load_lds(
        (const __attribute__((address_space(1))) void*)g,
        (__attribute__((address_space(3))) void*)l, 16, 0, 0);
}

// ---------------------------------------------------------------------------
// bf16 MFMA GEMM: Cb = A1@W1t^T [+ A2@W2t^T] + bias (bf16 out, optional relu).
// Optional fused BN stats: per-column sum/sumsq of fp32 (acc+bias) -> atomics.
// A [Nr,K] bf16 row-major; Wt [M,K] bf16 row-major. 128x128 tile, 4 waves.
// BK=64, global_load_lds staging into linear LDS with XOR-swizzled source
// (chunk ^= row&7), matching XOR on ds_read_b128 -> conflict-free fragments.
// Epilogue stages C tile in LDS (stride 136) -> coalesced 16B/lane stores.
// NOTE: all acc[][] indices MUST be compile-time (rule #20: runtime index
// demotes the accumulator to scratch and poisons the whole main loop).
// ---------------------------------------------------------------------------
__global__ __launch_bounds__(256) void gemm_mfma(
    const unsigned short* __restrict__ A1, const unsigned short* __restrict__ W1t,
    const unsigned short* __restrict__ A2, const unsigned short* __restrict__ W2t,
    const float* __restrict__ bias, unsigned short* __restrict__ Cb,
    float* __restrict__ bnsum, float* __restrict__ bnsq,
    int Nr, int K, int M, int relu)
{
    __shared__ unsigned short smem[17408];   // A[128][64] | B[128][64] ; reused as C[128][136]
    __shared__ float s_stat[256];            // 128 sum + 128 sumsq
    unsigned short* sA = smem;               // 8192 ushorts
    unsigned short* sB = smem + 8192;
    const int t = threadIdx.x;
    const int wave = t >> 6, lane = t & 63;
    const int wr = (wave >> 1) * 64, wc = (wave & 1) * 64;
    const int c0 = blockIdx.x * 128, r0 = blockIdx.y * 128;
    const int lm = lane & 15, lq = lane >> 4;
    const int l8 = lane >> 3;                 // 0..7 (row within 8-row segment)
    const int gsw8 = ((lane & 7) ^ l8) * 8;   // pre-swizzled source chunk (elements)
    f32x4 acc[4][4] = {};

    s_stat[t] = 0.f;  // visible before epilogue via in-loop barriers

    const int npass = (A2 != nullptr) ? 2 : 1;
    for (int pass = 0; pass < npass; ++pass) {
        const unsigned short* __restrict__ A = pass ? A2 : A1;
        const unsigned short* __restrict__ W = pass ? W2t : W1t;
        for (int k0 = 0; k0 < K; k0 += 64) {
            #pragma unroll
            for (int s = 0; s < 4; ++s) {
                const int seg = (wave << 2) + s;        // 0..15
                const int tr = (seg << 3) + l8;         // tile row 0..127
                int gr = r0 + tr; if (gr >= Nr) gr = Nr - 1;
                gload16(A + (long)gr * K + k0 + gsw8, sA + (seg << 9));
                int gc = c0 + tr; if (gc >= M) gc = M - 1;
                gload16(W + (long)gc * K + k0 + gsw8, sB + (seg << 9));
            }
            __syncthreads();
            #pragma unroll
            for (int kk = 0; kk < 2; ++kk) {
                const int pc = (((kk << 2) | lq) ^ (lm & 7)) << 3;  // phys chunk (elements)
                bf8v af[4], bf[4];
                #pragma unroll
                for (int i = 0; i < 4; ++i) {
                    const int ra = wr + (i << 4) + lm;
                    af[i] = *(const bf8v*)(sA + (ra << 6) + pc);
                    const int rb = wc + (i << 4) + lm;
                    bf[i] = *(const bf8v*)(sB + (rb << 6) + pc);
                }
                #pragma unroll
                for (int i = 0; i < 4; ++i)
                    #pragma unroll
                    for (int j = 0; j < 4; ++j)
                        acc[i][j] = __builtin_amdgcn_mfma_f32_16x16x32_bf16(
                            af[i], bf[j], acc[i][j], 0, 0, 0);
            }
            __syncthreads();
        }
    }

    const bool do_stats = (bnsum != nullptr);
    unsigned short* sC = smem;               // [128][136] bf16

    // ---- epilogue phase 1: bias/relu, BN partial stats, stage C tile in LDS
    #pragma unroll
    for (int j = 0; j < 4; ++j) {            // compile-time only (rule #20!)
        const int lcol = wc + (j << 4) + lm;
        const int col = c0 + lcol;
        const float bi = (col < M) ? bias[col] : 0.f;
        float ls = 0.f, lss = 0.f;
        #pragma unroll
        for (int i = 0; i < 4; ++i) {
            const int lrow = wr + (i << 4) + (lq << 2);
            #pragma unroll
            for (int r = 0; r < 4; ++r) {
                float v = acc[i][j][r] + bi;
                if (r0 + lrow + r < Nr) { ls += v; lss += v * v; }
                sC[(lrow + r) * 136 + lcol] = f2b(relu ? fmaxf(v, 0.f) : v);
            }
        }
        if (do_stats && col < M) {
            atomicAdd(&s_stat[lcol], ls);
            atomicAdd(&s_stat[128 + lcol], lss);
        }
    }
    __syncthreads();
    if (do_stats && t < 128) {
        int col = c0 + t;
        if (col < M) {
            atomicAdd(&bnsum[col], s_stat[t]);
            atomicAdd(&bnsq[col], s_stat[128 + t]);
        }
    }
    // ---- epilogue phase 2: coalesced row-major stores (16B/lane)
    #pragma unroll
    for (int it = 0; it < 8; ++it) {
        const int idx = (it << 8) + t;       // 0..2047
        const int lrow = idx >> 4;           // 0..127
        const int ch = idx & 15;             // 16B chunk in 256B row
        const int rowg = r0 + lrow;
        const int col = c0 + (ch << 3);
        if (rowg < Nr && col < M)
            *(bf8v*)(Cb + (long)rowg * M + col) =
                *(const bf8v*)(sC + lrow * 136 + (ch << 3));
    }
}

// ---------------------------------------------------------------------------
// Weight convert+transpose: W [L][K][M] fp32 -> Wt [L][M][K] bf16
// ---------------------------------------------------------------------------
__global__ void wt_convert(const float* __restrict__ W, unsigned short* __restrict__ Wt,
                           int total, int K, int M)
{
    int idx = blockIdx.x * 256 + threadIdx.x;
    if (idx >= total) return;
    int l = idx / (K * M), rem = idx - l * K * M;
    int k = rem / M, m = rem - k * M;
    Wt[(long)l * K * M + (long)m * K + k] = f2b(W[idx]);
}

__global__ void f2b_vec(const float* __restrict__ X, unsigned short* __restrict__ Y, int n4)
{
    int idx = blockIdx.x * 256 + threadIdx.x;
    if (idx >= n4) return;
    float4 v = *(const float4*)(X + idx * 4);
    ushort4 o = {f2b(v.x), f2b(v.y), f2b(v.z), f2b(v.w)};
    *(ushort4*)(Y + idx * 4) = o;
}

// ---------------------------------------------------------------------------
// CSR construction
// ---------------------------------------------------------------------------
__global__ void count_edges_i(const int* __restrict__ col, int* __restrict__ cnt, int E)
{
    int e = blockIdx.x * 256 + threadIdx.x;
    if (e < E) atomicAdd(&cnt[col[e]], 1);
}

__global__ __launch_bounds__(1024) void exscan_csr(const int* __restrict__ cnt,
                                                   int* __restrict__ offs, int n)
{
    __shared__ int s[1024];
    const int t = threadIdx.x;
    const int chunk = (n + 1023) >> 10;
    int lo = t * chunk, hi = lo + chunk;
    if (lo > n) lo = n;
    if (hi > n) hi = n;
    int sum = 0;
    for (int i = lo; i < hi; ++i) sum += cnt[i];
    s[t] = sum;
    __syncthreads();
    for (int d = 1; d < 1024; d <<= 1) {
        int o = (t >= d) ? s[t - d] : 0;
        __syncthreads();
        s[t] += o;
        __syncthreads();
    }
    int base = (t == 0) ? 0 : s[t - 1];
    for (int i = lo; i < hi; ++i) { offs[i] = base; base += cnt[i]; }
    if (t == 1023) offs[n] = s[1023];
}

__global__ void fill_csr(const int* __restrict__ row, const int* __restrict__ col,
                         const int* __restrict__ offs, int* __restrict__ cursor,
                         int* __restrict__ csr_rows, int E)
{
    int e = blockIdx.x * 256 + threadIdx.x;
    if (e < E) {
        int c = col[e];
        int p = offs[c] + atomicAdd(&cursor[c], 1);
        csr_rows[p] = row[e];
    }
}

__global__ void inv_from_cnt(const int* __restrict__ cnt, float* __restrict__ inv, int n)
{
    int i = blockIdx.x * 256 + threadIdx.x;
    if (i < n) inv[i] = 1.0f / fmaxf((float)cnt[i], 1.0f);
}

// ---------------------------------------------------------------------------
// CSR gather-mean in bf16: 8 nodes/block, 48 lanes/node, us8/lane, unroll x4
// ---------------------------------------------------------------------------
__global__ __launch_bounds__(384) void agg_gather(
    const unsigned short* __restrict__ hb, const int* __restrict__ csr_rows,
    const int* __restrict__ offs, const float* __restrict__ inv,
    unsigned short* __restrict__ aggb, int N)
{
    int g = threadIdx.x / 48;
    int lane = threadIdx.x - g * 48;
    int node = blockIdx.x * 8 + g;
    if (node >= N) return;
    const int lo = offs[node], hi = offs[node + 1];
    float s[8] = {};
    int e = lo;
    for (; e + 3 < hi; e += 4) {
        int r0 = csr_rows[e], r1 = csr_rows[e + 1];
        int r2 = csr_rows[e + 2], r3 = csr_rows[e + 3];
        us8 v0 = *(const us8*)(hb + (long)r0 * H + lane * 8);
        us8 v1 = *(const us8*)(hb + (long)r1 * H + lane * 8);
        us8 v2 = *(const us8*)(hb + (long)r2 * H + lane * 8);
        us8 v3 = *(const us8*)(hb + (long)r3 * H + lane * 8);
        #pragma unroll
        for (int q = 0; q < 8; ++q)
            s[q] += (b2f(v0[q]) + b2f(v1[q])) + (b2f(v2[q]) + b2f(v3[q]));
    }
    for (; e < hi; ++e) {
        us8 v = *(const us8*)(hb + (long)csr_rows[e] * H + lane * 8);
        #pragma unroll
        for (int q = 0; q < 8; ++q) s[q] += b2f(v[q]);
    }
    float sc = inv[node];
    us8 o;
    #pragma unroll
    for (int q = 0; q < 8; ++q) o[q] = f2b(s[q] * sc);
    *(us8*)(aggb + (long)node * H + lane * 8) = o;
}

// ---------------------------------------------------------------------------
// Fused BN finalize+apply: outb = relu(X*scale+shift) [+S]; optional fp32 copy
// X is bf16 (pre-BN); stats were accumulated in fp32 by the GEMM epilogue.
// ---------------------------------------------------------------------------
__global__ __launch_bounds__(256) void bn_apply(
    const unsigned short* __restrict__ X, const float* __restrict__ bnsum,
    const float* __restrict__ bnsq, const float* __restrict__ g,
    const float* __restrict__ b, const unsigned short* __restrict__ S,
    unsigned short* __restrict__ outb, float* __restrict__ outf,
    int Nr, int total4)
{
    __shared__ float sc[H], sh[H];
    const int t = threadIdx.x;
    for (int j = t; j < H; j += 256) {
        float mu  = bnsum[j] / (float)Nr;
        float var = bnsq[j] / (float)Nr - mu * mu;
        float s   = g[j] * rsqrtf(fmaxf(var, 0.f) + EPS);
        sc[j] = s;
        sh[j] = b[j] - mu * s;
    }
    __syncthreads();
    int idx = blockIdx.x * 256 + t;
    if (idx >= total4) return;
    int base = idx * 4;
    int j = base % H;
    ushort4 v = *(const ushort4*)(X + base);
    float o0 = fmaxf(b2f(v.x) * sc[j + 0] + sh[j + 0], 0.f);
    float o1 = fmaxf(b2f(v.y) * sc[j + 1] + sh[j + 1], 0.f);
    float o2 = fmaxf(b2f(v.z) * sc[j + 2] + sh[j + 2], 0.f);
    float o3 = fmaxf(b2f(v.w) * sc[j + 3] + sh[j + 3], 0.f);
    if (S) {
        ushort4 s4 = *(const ushort4*)(S + base);
        o0 += b2f(s4.x); o1 += b2f(s4.y); o2 += b2f(s4.z); o3 += b2f(s4.w);
    }
    ushort4 o = {f2b(o0), f2b(o1), f2b(o2), f2b(o3)};
    *(ushort4*)(outb + base) = o;
    if (outf) {
        float4 of = {o0, o1, o2, o3};
        *(float4*)(outf + base) = of;
    }
}

// ---------------------------------------------------------------------------
// Final tiny layer: out[N,2] = m2[N,96] @ W3[96,2] + b3
// ---------------------------------------------------------------------------
__global__ void mlp3(const unsigned short* __restrict__ m2, const float* __restrict__ W3,
                     const float* __restrict__ b3, float* __restrict__ out, int N)
{
    int n = blockIdx.x * 256 + threadIdx.x;
    if (n >= N) return;
    float a0 = b3[0], a1 = b3[1];
    const unsigned short* r = m2 + (long)n * 96;
    #pragma unroll 4
    for (int k = 0; k < 96; ++k) {
        float v = b2f(r[k]);
        a0 += v * W3[k * 2];
        a1 += v * W3[k * 2 + 1];
    }
    out[n * 2 + 0] = a0;
    out[n * 2 + 1] = a1;
}

// ---------------------------------------------------------------------------
extern "C" void kernel_launch(void* const* d_in, const int* in_sizes, int n_in,
                              void* d_out, int out_size, void* d_ws, size_t ws_size,
                              hipStream_t stream)
{
    const float* x     = (const float*)d_in[0];
    const int*   ei    = (const int*)d_in[1];
    const float* W_in  = (const float*)d_in[2];
    const float* b_in  = (const float*)d_in[3];
    const float* bn0_g = (const float*)d_in[4];
    const float* bn0_b = (const float*)d_in[5];
    const float* Wl    = (const float*)d_in[6];
    const float* bl    = (const float*)d_in[7];
    const float* Wr    = (const float*)d_in[8];
    const float* bn_g  = (const float*)d_in[9];
    const float* bn_b  = (const float*)d_in[10];
    const float* Wskip = (const float*)d_in[11];
    const float* bskip = (const float*)d_in[12];
    const float* W1    = (const float*)d_in[13];
    const float* b1    = (const float*)d_in[14];
    const float* W2    = (const float*)d_in[15];
    const float* b2    = (const float*)d_in[16];
    const float* W3    = (const float*)d_in[17];
    const float* b3    = (const float*)d_in[18];

    const int DIN = 256;
    const int N = in_sizes[0] / DIN;
    const int E = in_sizes[1] / 2;
    const int* row = ei;
    const int* col = ei + E;
    const long NH = (long)N * H;

    // workspace layout: 16B-aligned bf16 buffers first, then weights, then ints
    unsigned short* tmp      = (unsigned short*)d_ws;             // [N,H] pre-BN
    unsigned short* hb       = tmp + NH;                          // [N,H]
    unsigned short* aggb     = hb + NH;                           // [N,H]
    unsigned short* Sbuf     = aggb + NH;                         // [N,H]
    unsigned short* xb       = Sbuf + NH;                         // [N,DIN]
    unsigned short* Wint     = xb + (long)N * DIN;                // [H,DIN]
    unsigned short* Wlt      = Wint + (long)H * DIN;              // 6 [H,H]
    unsigned short* Wrt      = Wlt + 6L * H * H;
    unsigned short* Wskipt   = Wrt + 6L * H * H;                  // 3 [H,H]
    unsigned short* W1t      = Wskipt + 3L * H * H;               // [192,H]
    unsigned short* W2t      = W1t + 192L * H;                    // [96,192]
    float*          inv      = (float*)(W2t + 96L * 192);
    int*            offs     = (int*)(inv + N);                   // N+1
    int*            csr_rows = offs + (N + 1);                    // E
    int*            cnt      = csr_rows + E;                      // N (zeroed)
    int*            cursor   = cnt + N;                           // N (zeroed)
    float*          stats    = (float*)(cursor + N);              // 14*H (zeroed)
    float* out = (float*)d_out;
    float* emb = out + (long)N * 2;

    dim3 blk(256);
    const int rg128 = (N + 127) / 128;
    const int app_grid = (int)((NH / 4 + 255) / 256);

    // single upfront zero of cnt+cursor+stats
    hipMemsetAsync(cnt, 0, (2L * N + 14 * H) * sizeof(float), stream);

    // ---- CSR build
    count_edges_i<<<(E + 255) / 256, blk, 0, stream>>>(col, cnt, E);
    exscan_csr<<<1, 1024, 0, stream>>>(cnt, offs, N);
    inv_from_cnt<<<(N + 255) / 256, blk, 0, stream>>>(cnt, inv, N);
    fill_csr<<<(E + 255) / 256, blk, 0, stream>>>(row, col, offs, cursor, csr_rows, E);

    // ---- weight convert+transpose
    {
        int n1 = H * DIN;
        wt_convert<<<(n1 + 255) / 256, blk, 0, stream>>>(W_in, Wint, n1, DIN, H);
        int n2 = 6 * H * H;
        wt_convert<<<(n2 + 255) / 256, blk, 0, stream>>>(Wl, Wlt, n2, H, H);
        wt_convert<<<(n2 + 255) / 256, blk, 0, stream>>>(Wr, Wrt, n2, H, H);
        int n3 = 3 * H * H;
        wt_convert<<<(n3 + 255) / 256, blk, 0, stream>>>(Wskip, Wskipt, n3, H, H);
        int n4 = H * 192;
        wt_convert<<<(n4 + 255) / 256, blk, 0, stream>>>(W1, W1t, n4, H, 192);
        int n5 = 192 * 96;
        wt_convert<<<(n5 + 255) / 256, blk, 0, stream>>>(W2, W2t, n5, 192, 96);
    }

    // ---- input layer: x->bf16 -> GEMM(+stats0) -> bn_apply -> hb
    {
        int n4 = N * DIN / 4;
        f2b_vec<<<(n4 + 255) / 256, blk, 0, stream>>>(x, xb, n4);
    }
    gemm_mfma<<<dim3(3, rg128), blk, 0, stream>>>(
        xb, Wint, nullptr, nullptr, b_in, tmp, stats, stats + H, N, DIN, H, 0);
    bn_apply<<<app_grid, blk, 0, stream>>>(
        tmp, stats, stats + H, bn0_g, bn0_b, nullptr, hb, nullptr, N, (int)(NH / 4));

    // ---- 6 SAGE layers
    int skip_idx = 0;
    for (int i = 0; i < 6; ++i) {
        float* bs = stats + (i + 1) * 2 * H;
        agg_gather<<<(N + 7) / 8, 384, 0, stream>>>(hb, csr_rows, offs, inv, aggb, N);

        // tmp = agg@Wl + h@Wr + bl  (+ fused BN stats)
        gemm_mfma<<<dim3(3, rg128), blk, 0, stream>>>(
            aggb, Wlt + (long)i * H * H, hb, Wrt + (long)i * H * H,
            bl + i * H, tmp, bs, bs + H, N, H, H, 0);

        const unsigned short* S = nullptr;
        if ((i & 1) == 1) {
            // separate skip GEMM: Sbuf = h@Wskip + bskip (no stats)
            gemm_mfma<<<dim3(3, rg128), blk, 0, stream>>>(
                hb, Wskipt + (long)skip_idx * H * H, nullptr, nullptr,
                bskip + skip_idx * H, Sbuf, nullptr, nullptr, N, H, H, 0);
            skip_idx++;
            S = Sbuf;
        }
        bn_apply<<<app_grid, blk, 0, stream>>>(
            tmp, bs, bs + H, bn_g + i * H, bn_b + i * H, S, hb,
            (i == 5) ? emb : nullptr, N, (int)(NH / 4));
    }

    // ---- MLP head
    unsigned short* m1b = aggb;    // [N,192] bf16
    unsigned short* m2b = tmp;     // [N,96] bf16
    gemm_mfma<<<dim3(2, rg128), blk, 0, stream>>>(
        hb, W1t, nullptr, nullptr, b1, m1b, nullptr, nullptr, N, H, 192, 1);
    gemm_mfma<<<dim3(1, rg128), blk, 0, stream>>>(
        m1b, W2t, nullptr, nullptr, b2, m2b, nullptr, nullptr, N, 192, 96, 1);
    mlp3<<<(N + 255) / 256, blk, 0, stream>>>(m2b, W3, b3, out, N);
}